// Round 4
// baseline (1057.434 us; speedup 1.0000x reference)
//
#include <hip/hip_runtime.h>

#define SEQ    2048
#define BATCH  2
#define NHQ    32
#define NHKV   8
#define DHEAD  128
#define QSCALE 0.08838834764831845f   // 1/sqrt(128)

typedef __fp16 f16;
typedef f16 f16x2 __attribute__((ext_vector_type(2)));
typedef f16 f16x4 __attribute__((ext_vector_type(4)));
typedef f16 f16x8 __attribute__((ext_vector_type(8)));
typedef float f32x4 __attribute__((ext_vector_type(4)));

// LDS map (halfs): [K0 4096][K1 4096][V0 4096][V1 4096][P 4x640] = 37888 B.
// K tile: 32 rows x 128 halfs (256B row = 32 granules of 8B), phys granule
//   = logical ^ (2*(row&15))  -> conflict-free b64 writes + b128 reads.
// Vt tile: 128 rows(d) x 32 halfs (64B row = 8 granules), phys granule
//   = logical ^ (2*(row&3))   -> 2-way u16 writes (free), conflict-free b128.
// P: per-wave 16 rows x 40 halfs (80B) -> conflict-free b64 write / b128 read.
#define KBUF 4096
#define VBUF 4096
#define PBASE 16384
#define EPSTRIDE 132                // floats per epilogue row (128 + 4 pad)

__global__ __launch_bounds__(256, 4) void attn_fwd(const float* __restrict__ Q,
                                                   const float* __restrict__ K,
                                                   const float* __restrict__ V,
                                                   float* __restrict__ O) {
  const int qt  = gridDim.x - 1 - blockIdx.x;   // heavy blocks first
  const int bh  = blockIdx.y;
  const int b   = bh >> 5;
  const int hq  = bh & 31;
  const int hkv = hq >> 2;
  const int t    = threadIdx.x;
  const int wave = t >> 6;
  const int lane = t & 63;
  const int col  = lane & 15;
  const int quad = lane >> 4;

  const int q_base = qt * 64 + wave * 16;
  const int qrs = BATCH * NHQ * DHEAD;    // 8192
  const int krs = BATCH * NHKV * DHEAD;   // 2048

  const float* Qp = Q + ((size_t)b * NHQ  + hq ) * DHEAD;
  const float* Kp = K + ((size_t)b * NHKV + hkv) * DHEAD;
  const float* Vp = V + ((size_t)b * NHKV + hkv) * DHEAD;
  float*       Op = O + ((size_t)b * NHQ  + hq ) * DHEAD;

  __shared__ __align__(16) f16 smem[PBASE + 4 * 640];

  // ---- Q fragments (B-operand of 16x16x32: B[n=col][k=quad*8+j]), pre-scaled
  f16x8 qf[4];
  {
    const float* qsrc = Qp + (size_t)(q_base + col) * qrs + quad * 8;
    #pragma unroll
    for (int c = 0; c < 4; ++c) {
      float4 a = *(const float4*)(qsrc + c * 32);
      float4 e = *(const float4*)(qsrc + c * 32 + 4);
      f16x2 p0 = __builtin_amdgcn_cvt_pkrtz(a.x * QSCALE, a.y * QSCALE);
      f16x2 p1 = __builtin_amdgcn_cvt_pkrtz(a.z * QSCALE, a.w * QSCALE);
      f16x2 p2 = __builtin_amdgcn_cvt_pkrtz(e.x * QSCALE, e.y * QSCALE);
      f16x2 p3 = __builtin_amdgcn_cvt_pkrtz(e.z * QSCALE, e.w * QSCALE);
      qf[c][0] = p0[0]; qf[c][1] = p0[1]; qf[c][2] = p1[0]; qf[c][3] = p1[1];
      qf[c][4] = p2[0]; qf[c][5] = p2[1]; qf[c][6] = p3[0]; qf[c][7] = p3[1];
    }
  }

  f32x4 oacc[8];
  #pragma unroll
  for (int h = 0; h < 8; ++h) oacc[h] = (f32x4){0.f, 0.f, 0.f, 0.f};
  float m_i = -__builtin_inff();
  float l_i = 0.f;

  const int nt_blk = 2 * qt + 2;                 // block-uniform trip count
  const int nt_w   = ((q_base + 15) >> 5) + 1;   // this wave's causal tiles

  // ---- staging coordinates ----
  const int ktk = t >> 5, ktd = (t & 31) * 4, kg = t & 31;  // K: f16x4 granule
  const int vk  = t & 31, vd0 = t >> 5;                     // V: scalar f32
  const int vwc = (((vk >> 2) ^ (2 * (vd0 & 3))) << 3) + (vk & 3) * 2;

  // ---- per-lane fragment read offsets (bytes, constant across tiles) ----
  int kro[4];
  #pragma unroll
  for (int c = 0; c < 4; ++c)
    kro[c] = col * 256 + (((8 * c + 2 * quad) ^ (2 * col)) << 3);
  const int vro = col * 64 + (((2 * quad) ^ (2 * (col & 3))) << 3);
  char* pw8 = (char*)(smem + PBASE + wave * 640);
  const int pwo = col * 80 + quad * 8;    // P b64 write offset
  const int pro = col * 80 + quad * 16;   // P b128 read offset

  float4 kr[4];
  float  vr[16];

  // prologue: global loads for tile 0
  #pragma unroll
  for (int ro = 0; ro < 4; ++ro)
    kr[ro] = *(const float4*)(Kp + (size_t)(ktk + ro * 8) * krs + ktd);
  #pragma unroll
  for (int ro = 0; ro < 16; ++ro)
    vr[ro] = Vp[(size_t)vk * krs + ro * 8 + vd0];

  for (int kt = 0; kt < nt_blk; ++kt) {
    const int bf = kt & 1;
    char* kb8 = (char*)(smem + bf * KBUF);
    char* vb8 = (char*)(smem + 2 * KBUF + bf * VBUF);

    // ---- stage tile kt (cvt + swizzled LDS write) ----
    #pragma unroll
    for (int ro = 0; ro < 4; ++ro) {
      const int r = ktk + ro * 8;
      f16x2 lo = __builtin_amdgcn_cvt_pkrtz(kr[ro].x, kr[ro].y);
      f16x2 hi = __builtin_amdgcn_cvt_pkrtz(kr[ro].z, kr[ro].w);
      f16x4 v4; v4[0] = lo[0]; v4[1] = lo[1]; v4[2] = hi[0]; v4[3] = hi[1];
      *(f16x4*)(kb8 + r * 256 + ((kg ^ (2 * (r & 15))) << 3)) = v4;
    }
    #pragma unroll
    for (int ro = 0; ro < 16; ++ro) {
      const int d = ro * 8 + vd0;
      *(f16*)(vb8 + d * 64 + vwc) = (f16)vr[ro];
    }

    // ---- issue next tile's global loads ----
    if (kt + 1 < nt_blk) {
      const int k0n = (kt + 1) * 32;
      #pragma unroll
      for (int ro = 0; ro < 4; ++ro)
        kr[ro] = *(const float4*)(Kp + (size_t)(k0n + ktk + ro * 8) * krs + ktd);
      #pragma unroll
      for (int ro = 0; ro < 16; ++ro)
        vr[ro] = Vp[(size_t)(k0n + vk) * krs + ro * 8 + vd0];
    }

    __syncthreads();

    if (kt < nt_w) {
      const int k0 = kt * 32;

      // ---- S^T = K Q^T : A = K rows (m=k), B = Q (n=q) ----
      f32x4 s0 = {0.f, 0.f, 0.f, 0.f}, s1 = {0.f, 0.f, 0.f, 0.f};
      #pragma unroll
      for (int c = 0; c < 4; ++c) {
        f16x8 ka = *(const f16x8*)(kb8 + kro[c]);
        s0 = __builtin_amdgcn_mfma_f32_16x16x32_f16(ka, qf[c], s0, 0, 0, 0);
      }
      #pragma unroll
      for (int c = 0; c < 4; ++c) {
        f16x8 ka = *(const f16x8*)(kb8 + kro[c] + 4096);
        s1 = __builtin_amdgcn_mfma_f32_16x16x32_f16(ka, qf[c], s1, 0, 0, 0);
      }

      // ---- causal mask (final 1-2 tiles only); q = col, k = quad*4+r ----
      const int qrow = q_base + col;
      if (k0 + 31 > q_base) {
        #pragma unroll
        for (int r = 0; r < 4; ++r) {
          if (k0 + quad * 4 + r      > qrow) s0[r] = -__builtin_inff();
          if (k0 + 16 + quad * 4 + r > qrow) s1[r] = -__builtin_inff();
        }
      }

      // ---- online softmax (reduce over k: in-register + 2 shuffles) ----
      float mx = fmaxf(fmaxf(fmaxf(s0[0], s0[1]), fmaxf(s0[2], s0[3])),
                       fmaxf(fmaxf(s1[0], s1[1]), fmaxf(s1[2], s1[3])));
      mx = fmaxf(mx, __shfl_xor(mx, 16, 64));
      mx = fmaxf(mx, __shfl_xor(mx, 32, 64));
      const float mnew  = fmaxf(m_i, mx);
      const float alpha = __expf(m_i - mnew);
      m_i = mnew;

      float e0[4], e1[4], rs = 0.f;
      #pragma unroll
      for (int r = 0; r < 4; ++r) {
        e0[r] = __expf(s0[r] - mnew);
        e1[r] = __expf(s1[r] - mnew);
        rs += e0[r] + e1[r];
      }
      rs += __shfl_xor(rs, 16, 64);
      rs += __shfl_xor(rs, 32, 64);
      l_i = l_i * alpha + rs;

      #pragma unroll
      for (int h = 0; h < 8; ++h) {
        oacc[h][0] *= alpha; oacc[h][1] *= alpha;
        oacc[h][2] *= alpha; oacc[h][3] *= alpha;
      }

      // ---- P^T: regroup k (quad*4+r -> quad*8+j) via wave-private LDS ----
      f16x2 a01 = __builtin_amdgcn_cvt_pkrtz(e0[0], e0[1]);
      f16x2 a23 = __builtin_amdgcn_cvt_pkrtz(e0[2], e0[3]);
      f16x2 b01 = __builtin_amdgcn_cvt_pkrtz(e1[0], e1[1]);
      f16x2 b23 = __builtin_amdgcn_cvt_pkrtz(e1[2], e1[3]);
      f16x4 pa; pa[0] = a01[0]; pa[1] = a01[1]; pa[2] = a23[0]; pa[3] = a23[1];
      f16x4 pb4; pb4[0] = b01[0]; pb4[1] = b01[1]; pb4[2] = b23[0]; pb4[3] = b23[1];
      *(f16x4*)(pw8 + pwo)      = pa;    // k = 4*quad..+3
      *(f16x4*)(pw8 + pwo + 32) = pb4;   // k = 16+4*quad..+3
      __asm__ volatile("s_waitcnt lgkmcnt(0)" ::: "memory");
      f16x8 pb = *(const f16x8*)(pw8 + pro);   // B[n=col][k=quad*8+j]
      __asm__ volatile("" ::: "memory");

      // ---- O^T += V^T P^T : one 16x16x32 per 16-d block ----
      #pragma unroll
      for (int h = 0; h < 8; ++h) {
        f16x8 va = *(const f16x8*)(vb8 + h * 1024 + vro);
        oacc[h] = __builtin_amdgcn_mfma_f32_16x16x32_f16(va, pb, oacc[h], 0, 0, 0);
      }
    }
  }

  __syncthreads();   // LDS no longer needed; reuse for epilogue transpose

  {
    float* ep = (float*)smem + wave * (16 * EPSTRIDE);   // wave-private
    const float invl = 1.0f / l_i;
    #pragma unroll
    for (int h = 0; h < 8; ++h) {
      f32x4 v = oacc[h];
      v[0] *= invl; v[1] *= invl; v[2] *= invl; v[3] *= invl;
      *(f32x4*)(ep + col * EPSTRIDE + h * 16 + quad * 4) = v;
    }
    __asm__ volatile("s_waitcnt lgkmcnt(0)" ::: "memory");  // wave-private only
    const int row = lane >> 2;
    const int d4  = lane & 3;
    #pragma unroll
    for (int c = 0; c < 8; ++c) {
      const int f = d4 + c * 4;
      float4 o = *(const float4*)(ep + row * EPSTRIDE + f * 4);
      *(float4*)(Op + (size_t)(q_base + row) * qrs + f * 4) = o;
    }
  }
}

extern "C" void kernel_launch(void* const* d_in, const int* in_sizes, int n_in,
                              void* d_out, int out_size, void* d_ws, size_t ws_size,
                              hipStream_t stream) {
  const float* Q = (const float*)d_in[0];
  const float* K = (const float*)d_in[1];
  const float* V = (const float*)d_in[2];
  float* O = (float*)d_out;
  (void)in_sizes; (void)n_in; (void)out_size; (void)d_ws; (void)ws_size;
  dim3 grid(SEQ / 64, BATCH * NHQ);
  attn_fwd<<<grid, dim3(256), 0, stream>>>(Q, K, V, O);
}

// Round 5
// 692.915 us; speedup vs baseline: 1.5261x; 1.5261x over previous
//
#include <hip/hip_runtime.h>

#define SEQ    2048
#define BATCH  2
#define NHQ    32
#define NHKV   8
#define DHEAD  128
#define QSC2   0.12751743f   // (1/sqrt(128)) * log2(e)  -> softmax in exp2 domain

typedef __fp16 f16;
typedef f16 f16x2 __attribute__((ext_vector_type(2)));
typedef f16 f16x4 __attribute__((ext_vector_type(4)));
typedef f16 f16x8 __attribute__((ext_vector_type(8)));
typedef float f32x4 __attribute__((ext_vector_type(4)));

// LDS (halfs): [K0 4096][K1 4096][V0 4352][V1 4352] = 33792 B.
// K tile: 32 x 128, 256B rows of 32 8B-granules, phys = logical ^ (2*(row&15))
//   -> conflict-free f16x4 writes and b128 reads  (validated round 4).
// Vt tile: 128 d-rows x 32 halfs + 2 pad (stride 34): coalesced float2 global
//   loads, 2-way (free) u16 transpose writes, ~2-way b32 reads (round 3).
#define KBUF 4096
#define VSTRIDE 34
#define VBUF (128 * VSTRIDE)
#define EPSTRIDE 132         // floats per epilogue row (128 + 4 pad)

__global__ __launch_bounds__(256, 3) void attn_fwd(const float* __restrict__ Q,
                                                   const float* __restrict__ K,
                                                   const float* __restrict__ V,
                                                   float* __restrict__ O) {
  const int qt  = gridDim.x - 1 - blockIdx.x;   // heavy blocks first
  const int bh  = blockIdx.y;
  const int b   = bh >> 5;
  const int hq  = bh & 31;
  const int hkv = hq >> 2;
  const int t    = threadIdx.x;
  const int wave = t >> 6;
  const int lane = t & 63;
  const int col  = lane & 15;
  const int quad = lane >> 4;

  const int q_base = qt * 128 + wave * 32;      // 32 q rows per wave
  const int qrs = BATCH * NHQ * DHEAD;          // 8192
  const int krs = BATCH * NHKV * DHEAD;         // 2048

  const float* Qp = Q + ((size_t)b * NHQ  + hq ) * DHEAD;
  const float* Kp = K + ((size_t)b * NHKV + hkv) * DHEAD;
  const float* Vp = V + ((size_t)b * NHKV + hkv) * DHEAD;
  float*       Op = O + ((size_t)b * NHQ  + hq ) * DHEAD;

  __shared__ __align__(16) f16 smem[2 * KBUF + 2 * VBUF];   // 33792 B

  // ---- Q fragments for two 16-row sub-tiles (B-operand: B[n=col][k=quad*8+j]),
  //      pre-scaled by (1/sqrt(D))*log2(e) ----
  f16x8 qfa[4], qfb[4];
  {
    const float* qA = Qp + (size_t)(q_base + col) * qrs + quad * 8;
    const float* qB = Qp + (size_t)(q_base + 16 + col) * qrs + quad * 8;
    #pragma unroll
    for (int c = 0; c < 4; ++c) {
      float4 a = *(const float4*)(qA + c * 32);
      float4 e = *(const float4*)(qA + c * 32 + 4);
      f16x2 p0 = __builtin_amdgcn_cvt_pkrtz(a.x * QSC2, a.y * QSC2);
      f16x2 p1 = __builtin_amdgcn_cvt_pkrtz(a.z * QSC2, a.w * QSC2);
      f16x2 p2 = __builtin_amdgcn_cvt_pkrtz(e.x * QSC2, e.y * QSC2);
      f16x2 p3 = __builtin_amdgcn_cvt_pkrtz(e.z * QSC2, e.w * QSC2);
      qfa[c][0] = p0[0]; qfa[c][1] = p0[1]; qfa[c][2] = p1[0]; qfa[c][3] = p1[1];
      qfa[c][4] = p2[0]; qfa[c][5] = p2[1]; qfa[c][6] = p3[0]; qfa[c][7] = p3[1];
    }
    #pragma unroll
    for (int c = 0; c < 4; ++c) {
      float4 a = *(const float4*)(qB + c * 32);
      float4 e = *(const float4*)(qB + c * 32 + 4);
      f16x2 p0 = __builtin_amdgcn_cvt_pkrtz(a.x * QSC2, a.y * QSC2);
      f16x2 p1 = __builtin_amdgcn_cvt_pkrtz(a.z * QSC2, a.w * QSC2);
      f16x2 p2 = __builtin_amdgcn_cvt_pkrtz(e.x * QSC2, e.y * QSC2);
      f16x2 p3 = __builtin_amdgcn_cvt_pkrtz(e.z * QSC2, e.w * QSC2);
      qfb[c][0] = p0[0]; qfb[c][1] = p0[1]; qfb[c][2] = p1[0]; qfb[c][3] = p1[1];
      qfb[c][4] = p2[0]; qfb[c][5] = p2[1]; qfb[c][6] = p3[0]; qfb[c][7] = p3[1];
    }
  }

  f32x4 oaccA[8], oaccB[8];
  #pragma unroll
  for (int h = 0; h < 8; ++h) {
    oaccA[h] = (f32x4){0.f, 0.f, 0.f, 0.f};
    oaccB[h] = (f32x4){0.f, 0.f, 0.f, 0.f};
  }
  float m0 = -__builtin_inff(), l0 = 0.f;
  float m1 = -__builtin_inff(), l1 = 0.f;

  const int nt_blk = 4 * qt + 4;                 // block-uniform trip count
  const int nt_w   = ((q_base + 31) >> 5) + 1;   // this wave's causal tiles

  // ---- staging coordinates ----
  const int ktk = t >> 5, ktd = (t & 31) * 4, kg = t & 31;   // K: f16x4 granule
  const int vtk = t >> 6, vtd = (t & 63) * 2;                // V: float2 rows

  // ---- fragment read offsets (bytes, constant across tiles) ----
  int kro[4];
  #pragma unroll
  for (int c = 0; c < 4; ++c)
    kro[c] = col * 256 + (((8 * c + 2 * quad) ^ (2 * col)) << 3);

  float4 kr[4];
  float2 vr2[8];

  // prologue: global loads for tile 0
  #pragma unroll
  for (int ro = 0; ro < 4; ++ro)
    kr[ro] = *(const float4*)(Kp + (size_t)(ktk + ro * 8) * krs + ktd);
  #pragma unroll
  for (int ro = 0; ro < 8; ++ro)
    vr2[ro] = *(const float2*)(Vp + (size_t)(vtk + ro * 4) * krs + vtd);

  for (int kt = 0; kt < nt_blk; ++kt) {
    const int bf = kt & 1;
    char* kb8 = (char*)(smem + bf * KBUF);
    f16*  vb  = smem + 2 * KBUF + bf * VBUF;

    // ---- stage tile kt ----
    #pragma unroll
    for (int ro = 0; ro < 4; ++ro) {
      const int r = ktk + ro * 8;
      f16x2 lo = __builtin_amdgcn_cvt_pkrtz(kr[ro].x, kr[ro].y);
      f16x2 hi = __builtin_amdgcn_cvt_pkrtz(kr[ro].z, kr[ro].w);
      f16x4 v4; v4[0] = lo[0]; v4[1] = lo[1]; v4[2] = hi[0]; v4[3] = hi[1];
      *(f16x4*)(kb8 + r * 256 + ((kg ^ (2 * (r & 15))) << 3)) = v4;
    }
    #pragma unroll
    for (int ro = 0; ro < 8; ++ro) {            // transposed: Vt[d][k]
      vb[(vtd    ) * VSTRIDE + vtk + ro * 4] = (f16)vr2[ro].x;
      vb[(vtd + 1) * VSTRIDE + vtk + ro * 4] = (f16)vr2[ro].y;
    }

    // ---- issue next tile's global loads ----
    if (kt + 1 < nt_blk) {
      const int k0n = (kt + 1) * 32;
      #pragma unroll
      for (int ro = 0; ro < 4; ++ro)
        kr[ro] = *(const float4*)(Kp + (size_t)(k0n + ktk + ro * 8) * krs + ktd);
      #pragma unroll
      for (int ro = 0; ro < 8; ++ro)
        vr2[ro] = *(const float2*)(Vp + (size_t)(k0n + vtk + ro * 4) * krs + vtd);
    }

    __syncthreads();

    if (kt < nt_w) {
      const int k0 = kt * 32;

      // ---- S^T = K Q^T for both sub-tiles (K fragments shared) ----
      f32x4 s0a = {0.f,0.f,0.f,0.f}, s1a = {0.f,0.f,0.f,0.f};
      f32x4 s0b = {0.f,0.f,0.f,0.f}, s1b = {0.f,0.f,0.f,0.f};
      #pragma unroll
      for (int c = 0; c < 4; ++c) {
        f16x8 ka = *(const f16x8*)(kb8 + kro[c]);
        s0a = __builtin_amdgcn_mfma_f32_16x16x32_f16(ka, qfa[c], s0a, 0, 0, 0);
        s0b = __builtin_amdgcn_mfma_f32_16x16x32_f16(ka, qfb[c], s0b, 0, 0, 0);
      }
      #pragma unroll
      for (int c = 0; c < 4; ++c) {
        f16x8 ka = *(const f16x8*)(kb8 + kro[c] + 4096);
        s1a = __builtin_amdgcn_mfma_f32_16x16x32_f16(ka, qfa[c], s1a, 0, 0, 0);
        s1b = __builtin_amdgcn_mfma_f32_16x16x32_f16(ka, qfb[c], s1b, 0, 0, 0);
      }

      // ---- causal mask: only the diagonal tile is partial ----
      const int qrowA = q_base + col;
      const int qrowB = q_base + 16 + col;
      if (k0 + 31 > q_base) {
        #pragma unroll
        for (int r = 0; r < 4; ++r) {
          const int kA = k0 + quad * 4 + r, kB = kA + 16;
          if (kA > qrowA) s0a[r] = -__builtin_inff();
          if (kB > qrowA) s1a[r] = -__builtin_inff();
          if (kA > qrowB) s0b[r] = -__builtin_inff();
          if (kB > qrowB) s1b[r] = -__builtin_inff();
        }
      }

      // ---- online softmax (exp2 domain), sub-tile A ----
      float mxa = fmaxf(fmaxf(fmaxf(s0a[0], s0a[1]), fmaxf(s0a[2], s0a[3])),
                        fmaxf(fmaxf(s1a[0], s1a[1]), fmaxf(s1a[2], s1a[3])));
      mxa = fmaxf(mxa, __shfl_xor(mxa, 16, 64));
      mxa = fmaxf(mxa, __shfl_xor(mxa, 32, 64));
      const float mnewA  = fmaxf(m0, mxa);
      const float alphaA = exp2f(m0 - mnewA);
      m0 = mnewA;
      float e0a[4], e1a[4], rsa = 0.f;
      #pragma unroll
      for (int r = 0; r < 4; ++r) {
        e0a[r] = exp2f(s0a[r] - mnewA);
        e1a[r] = exp2f(s1a[r] - mnewA);
        rsa += e0a[r] + e1a[r];
      }
      rsa += __shfl_xor(rsa, 16, 64);
      rsa += __shfl_xor(rsa, 32, 64);
      l0 = l0 * alphaA + rsa;

      // ---- sub-tile B ----
      float mxb = fmaxf(fmaxf(fmaxf(s0b[0], s0b[1]), fmaxf(s0b[2], s0b[3])),
                        fmaxf(fmaxf(s1b[0], s1b[1]), fmaxf(s1b[2], s1b[3])));
      mxb = fmaxf(mxb, __shfl_xor(mxb, 16, 64));
      mxb = fmaxf(mxb, __shfl_xor(mxb, 32, 64));
      const float mnewB  = fmaxf(m1, mxb);
      const float alphaB = exp2f(m1 - mnewB);
      m1 = mnewB;
      float e0b[4], e1b[4], rsb = 0.f;
      #pragma unroll
      for (int r = 0; r < 4; ++r) {
        e0b[r] = exp2f(s0b[r] - mnewB);
        e1b[r] = exp2f(s1b[r] - mnewB);
        rsb += e0b[r] + e1b[r];
      }
      rsb += __shfl_xor(rsb, 16, 64);
      rsb += __shfl_xor(rsb, 32, 64);
      l1 = l1 * alphaB + rsb;

      // ---- rescale accumulators ----
      #pragma unroll
      for (int h = 0; h < 8; ++h) {
        oaccA[h][0] *= alphaA; oaccA[h][1] *= alphaA;
        oaccA[h][2] *= alphaA; oaccA[h][3] *= alphaA;
        oaccB[h][0] *= alphaB; oaccB[h][1] *= alphaB;
        oaccB[h][2] *= alphaB; oaccB[h][3] *= alphaB;
      }

      // ---- P^T already in 16x16x16 B-operand layout (k = quad*4+j) ----
      f16x2 aa01 = __builtin_amdgcn_cvt_pkrtz(e0a[0], e0a[1]);
      f16x2 aa23 = __builtin_amdgcn_cvt_pkrtz(e0a[2], e0a[3]);
      f16x2 ab01 = __builtin_amdgcn_cvt_pkrtz(e1a[0], e1a[1]);
      f16x2 ab23 = __builtin_amdgcn_cvt_pkrtz(e1a[2], e1a[3]);
      f16x4 pa0; pa0[0]=aa01[0]; pa0[1]=aa01[1]; pa0[2]=aa23[0]; pa0[3]=aa23[1];
      f16x4 pa1; pa1[0]=ab01[0]; pa1[1]=ab01[1]; pa1[2]=ab23[0]; pa1[3]=ab23[1];
      f16x2 ba01 = __builtin_amdgcn_cvt_pkrtz(e0b[0], e0b[1]);
      f16x2 ba23 = __builtin_amdgcn_cvt_pkrtz(e0b[2], e0b[3]);
      f16x2 bb01 = __builtin_amdgcn_cvt_pkrtz(e1b[0], e1b[1]);
      f16x2 bb23 = __builtin_amdgcn_cvt_pkrtz(e1b[2], e1b[3]);
      f16x4 pb0; pb0[0]=ba01[0]; pb0[1]=ba01[1]; pb0[2]=ba23[0]; pb0[3]=ba23[1];
      f16x4 pb1; pb1[0]=bb01[0]; pb1[1]=bb01[1]; pb1[2]=bb23[0]; pb1[3]=bb23[1];

      // ---- O^T += V^T P^T  (V fragments shared across sub-tiles) ----
      #pragma unroll
      for (int h = 0; h < 8; ++h) {
        const f16* vr = vb + (h * 16 + col) * VSTRIDE + quad * 4;
        f16x2 x0 = *(const f16x2*)(vr);
        f16x2 x1 = *(const f16x2*)(vr + 2);
        f16x2 y0 = *(const f16x2*)(vr + 16);
        f16x2 y1 = *(const f16x2*)(vr + 18);
        f16x4 va0; va0[0]=x0[0]; va0[1]=x0[1]; va0[2]=x1[0]; va0[3]=x1[1];
        f16x4 va1; va1[0]=y0[0]; va1[1]=y0[1]; va1[2]=y1[0]; va1[3]=y1[1];
        oaccA[h] = __builtin_amdgcn_mfma_f32_16x16x16f16(va0, pa0, oaccA[h], 0, 0, 0);
        oaccA[h] = __builtin_amdgcn_mfma_f32_16x16x16f16(va1, pa1, oaccA[h], 0, 0, 0);
        oaccB[h] = __builtin_amdgcn_mfma_f32_16x16x16f16(va0, pb0, oaccB[h], 0, 0, 0);
        oaccB[h] = __builtin_amdgcn_mfma_f32_16x16x16f16(va1, pb1, oaccB[h], 0, 0, 0);
      }
    }
  }

  __syncthreads();   // LDS no longer needed; reuse for epilogue transpose

  {
    float* ep = (float*)smem + wave * (16 * EPSTRIDE);   // wave-private
    const int row = lane >> 2;
    const int d4  = lane & 3;
    #pragma unroll
    for (int st = 0; st < 2; ++st) {
      const float invl = st ? (1.0f / l1) : (1.0f / l0);
      #pragma unroll
      for (int h = 0; h < 8; ++h) {
        f32x4 v = st ? oaccB[h] : oaccA[h];
        v[0] *= invl; v[1] *= invl; v[2] *= invl; v[3] *= invl;
        *(f32x4*)(ep + col * EPSTRIDE + h * 16 + quad * 4) = v;
      }
      __asm__ volatile("s_waitcnt lgkmcnt(0)" ::: "memory");  // wave-private
      #pragma unroll
      for (int c = 0; c < 8; ++c) {
        const int f = d4 + c * 4;
        float4 o = *(const float4*)(ep + row * EPSTRIDE + f * 4);
        *(float4*)(Op + (size_t)(q_base + st * 16 + row) * qrs + f * 4) = o;
      }
      __asm__ volatile("s_waitcnt lgkmcnt(0)" ::: "memory");  // reads drained
    }
  }
}

extern "C" void kernel_launch(void* const* d_in, const int* in_sizes, int n_in,
                              void* d_out, int out_size, void* d_ws, size_t ws_size,
                              hipStream_t stream) {
  const float* Q = (const float*)d_in[0];
  const float* K = (const float*)d_in[1];
  const float* V = (const float*)d_in[2];
  float* O = (float*)d_out;
  (void)in_sizes; (void)n_in; (void)out_size; (void)d_ws; (void)ws_size;
  dim3 grid(SEQ / 128, BATCH * NHQ);
  attn_fwd<<<grid, dim3(256), 0, stream>>>(Q, K, V, O);
}